// Round 3
// baseline (132.682 us; speedup 1.0000x reference)
//
#include <hip/hip_runtime.h>
#include <math.h>

#define B      32
#define NSRC   4
#define T      64000
#define CH     16
#define NACC   20          // 10 gram + 4 c1 + 4 c2 + n1 + n2
#define KCOMB  16
#define NBLK   (B * CH)          // 512 blocks
#define TLEN4  ((T / CH) / 4)    // 1000 float4 per chunk per stream
#define CNT_BYTE_OFF (NBLK * NACC * 4)   // ticket counter lives after partials

// DPP controls
#define DPP_QX1   0xB1    // quad_perm(1,0,3,2)  == xor 1
#define DPP_QX2   0x4E    // quad_perm(2,3,0,1)  == xor 2
#define DPP_HMIRR 0x141   // row_half_mirror     (pairs 4-groups within 8)
#define DPP_MIRR  0x140   // row_mirror          (pairs 8-groups within 16)

template <int CTRL>
__device__ __forceinline__ float dpp_add(float v) {
    int x = __builtin_amdgcn_update_dpp(0, __float_as_int(v), CTRL, 0xF, 0xF, true);
    return v + __int_as_float(x);
}

__device__ __forceinline__ void accum20(float* __restrict__ acc,
        const float4 v0, const float4 v1, const float4 v2, const float4 v3,
        const float4 w1, const float4 w2)
{
    const float A0[4] = {v0.x, v0.y, v0.z, v0.w};
    const float A1[4] = {v1.x, v1.y, v1.z, v1.w};
    const float A2[4] = {v2.x, v2.y, v2.z, v2.w};
    const float A3[4] = {v3.x, v3.y, v3.z, v3.w};
    const float M1[4] = {w1.x, w1.y, w1.z, w1.w};
    const float M2[4] = {w2.x, w2.y, w2.z, w2.w};
#pragma unroll
    for (int j = 0; j < 4; j++) {
        float s0 = A0[j], s1 = A1[j], s2 = A2[j], s3 = A3[j];
        float x = M1[j], y = M2[j];
        acc[0]  = fmaf(s0, s0, acc[0]);
        acc[1]  = fmaf(s0, s1, acc[1]);
        acc[2]  = fmaf(s0, s2, acc[2]);
        acc[3]  = fmaf(s0, s3, acc[3]);
        acc[4]  = fmaf(s1, s1, acc[4]);
        acc[5]  = fmaf(s1, s2, acc[5]);
        acc[6]  = fmaf(s1, s3, acc[6]);
        acc[7]  = fmaf(s2, s2, acc[7]);
        acc[8]  = fmaf(s2, s3, acc[8]);
        acc[9]  = fmaf(s3, s3, acc[9]);
        acc[10] = fmaf(s0, x,  acc[10]);
        acc[11] = fmaf(s1, x,  acc[11]);
        acc[12] = fmaf(s2, x,  acc[12]);
        acc[13] = fmaf(s3, x,  acc[13]);
        acc[14] = fmaf(s0, y,  acc[14]);
        acc[15] = fmaf(s1, y,  acc[15]);
        acc[16] = fmaf(s2, y,  acc[16]);
        acc[17] = fmaf(s3, y,  acc[17]);
        acc[18] = fmaf(x,  x,  acc[18]);
        acc[19] = fmaf(y,  y,  acc[19]);
    }
}

__global__ __launch_bounds__(256) void mixit_fused_kernel(
    const float* __restrict__ est, const float* __restrict__ m1,
    const float* __restrict__ m2, float* __restrict__ ws,
    float* __restrict__ out)
{
    const int tid = threadIdx.x;
    const int b   = blockIdx.x / CH;
    const int ch  = blockIdx.x % CH;

    const float4* e0 = (const float4*)(est + (size_t)b * NSRC * T) + (size_t)ch * TLEN4;
    const float4* e1 = e0 + T / 4;
    const float4* e2 = e1 + T / 4;
    const float4* e3 = e2 + T / 4;
    const float4* p1 = (const float4*)(m1 + (size_t)b * T) + (size_t)ch * TLEN4;
    const float4* p2 = (const float4*)(m2 + (size_t)b * T) + (size_t)ch * TLEN4;

    float acc[NACC];
#pragma unroll
    for (int i = 0; i < NACC; i++) acc[i] = 0.0f;

    // software-pipelined main loop: prefetch iteration i+1 while computing i
    int i = tid;                       // tid < 256 <= TLEN4, first load always valid
    float4 c0 = e0[i], c1 = e1[i], c2 = e2[i], c3 = e3[i], c4 = p1[i], c5 = p2[i];
    while (true) {
        const int inext = i + 256;
        const bool hn = inext < TLEN4;
        float4 n0, n1v, n2v, n3, n4, n5;
        if (hn) {
            n0 = e0[inext]; n1v = e1[inext]; n2v = e2[inext];
            n3 = e3[inext]; n4  = p1[inext]; n5  = p2[inext];
        }
        accum20(acc, c0, c1, c2, c3, c4, c5);
        if (!hn) break;
        c0 = n0; c1 = n1v; c2 = n2v; c3 = n3; c4 = n4; c5 = n5;
        i = inext;
    }

    // wave reduce: 4 DPP adds (VALU) + one xor-16 swizzle -> lanes 0 and 32
    // hold the two half-wave sums.
#pragma unroll
    for (int a = 0; a < NACC; a++) {
        float v = acc[a];
        v = dpp_add<DPP_QX1>(v);     // + xor1
        v = dpp_add<DPP_QX2>(v);     // + xor2  -> 4-group sums
        v = dpp_add<DPP_HMIRR>(v);   // -> 8-group sums
        v = dpp_add<DPP_MIRR>(v);    // -> 16-group sums
        int x = __builtin_amdgcn_ds_swizzle(__float_as_int(v), 0x401F); // xor16
        acc[a] = v + __int_as_float(x);
    }

    const int lane = tid & 63;
    const int wave = tid >> 6;
    __shared__ float red[8][NACC];
    if (lane == 0 || lane == 32) {
        const int r = wave * 2 + (lane >> 5);
#pragma unroll
        for (int a = 0; a < NACC; a++) red[r][a] = acc[a];
    }
    __syncthreads();
    if (tid < NACC) {
        float s = 0.0f;
#pragma unroll
        for (int r = 0; r < 8; r++) s += red[r][tid];
        ws[(size_t)blockIdx.x * NACC + tid] = s;   // deterministic partials
    }

    // ---- last-block finalize (device-scope fence + ticket) ----
    __threadfence();                    // push partials to device coherence point
    __syncthreads();
    __shared__ int isLast;
    if (tid == 0) {
        unsigned* cnt = (unsigned*)((char*)ws + CNT_BYTE_OFF);
        unsigned t = __hip_atomic_fetch_add(cnt, 1u, __ATOMIC_ACQ_REL,
                                            __HIP_MEMORY_SCOPE_AGENT);
        isLast = (t == NBLK - 1) ? 1 : 0;
    }
    __syncthreads();
    if (!isLast) return;
    __threadfence();                    // acquire side: invalidate stale lines

    __shared__ float sums[B * NACC];
    for (int p = tid; p < B * NACC; p += 256) {
        const int bb = p / NACC, a = p % NACC;
        float s = 0.0f;
#pragma unroll
        for (int c = 0; c < CH; c++)
            s += ws[(size_t)(bb * CH + c) * NACC + a];
        sums[p] = s;
    }
    __syncthreads();

    __shared__ float losses[KCOMB];
    if (tid < KCOMB) {
        const int k = tid;
        const float k0 = (float)((k >> 3) & 1);
        const float k1 = (float)((k >> 2) & 1);
        const float k2 = (float)((k >> 1) & 1);
        const float k3 = (float)(k & 1);
        const float u0 = 1.0f - k0, u1 = 1.0f - k1, u2 = 1.0f - k2, u3 = 1.0f - k3;

        float loss = 0.0f;
        for (int bb = 0; bb < B; bb++) {
            const float* a = sums + bb * NACC;
            float g00 = a[0], g01 = a[1], g02 = a[2], g03 = a[3];
            float g11 = a[4], g12 = a[5], g13 = a[6];
            float g22 = a[7], g23 = a[8], g33 = a[9];

            float q0 = k0*k0*g00 + k1*k1*g11 + k2*k2*g22 + k3*k3*g33
                     + 2.0f*(k0*k1*g01 + k0*k2*g02 + k0*k3*g03
                           + k1*k2*g12 + k1*k3*g13 + k2*k3*g23);
            float q1 = u0*u0*g00 + u1*u1*g11 + u2*u2*g22 + u3*u3*g33
                     + 2.0f*(u0*u1*g01 + u0*u2*g02 + u0*u3*g03
                           + u1*u2*g12 + u1*u3*g13 + u2*u3*g23);
            float d1 = k0*a[10] + k1*a[11] + k2*a[12] + k3*a[13];
            float d2 = u0*a[14] + u1*a[15] + u2*a[16] + u3*a[17];

            float a0 = q0 - 2.0f*d1 + a[18];
            float a1 = q1 - 2.0f*d2 + a[19];

            // b==0 -> log10(0) = -inf -> loss +inf (IEEE), never the min
            loss += 10.0f * (log10f(fmaf(30.0f, q0, a0)) - log10f(q0));
            loss += 10.0f * (log10f(fmaf(30.0f, q1, a1)) - log10f(q1));
        }
        losses[k] = loss;
    }
    __syncthreads();

    if (tid == 0) {
        float best = losses[0];
        int bi = 0;
        for (int k = 1; k < KCOMB; k++)
            if (losses[k] < best) { best = losses[k]; bi = k; }
        out[0] = (float)bi;
        out[1] = best;
    }
}

extern "C" void kernel_launch(void* const* d_in, const int* in_sizes, int n_in,
                              void* d_out, int out_size, void* d_ws, size_t ws_size,
                              hipStream_t stream) {
    const float* est = (const float*)d_in[0];
    const float* m1  = (const float*)d_in[1];
    const float* m2  = (const float*)d_in[2];
    float* ws  = (float*)d_ws;
    float* out = (float*)d_out;

    // zero the ticket counter (graph-capturable memset node)
    (void)hipMemsetAsync((char*)d_ws + CNT_BYTE_OFF, 0, 4, stream);
    mixit_fused_kernel<<<NBLK, 256, 0, stream>>>(est, m1, m2, ws, out);
}

// Round 4
// 90.962 us; speedup vs baseline: 1.4587x; 1.4587x over previous
//
#include <hip/hip_runtime.h>
#include <math.h>

#define B      32
#define NSRC   4
#define T      64000
#define CH     64                // T-chunks per batch -> 32*64 = 2048 blocks (8/CU)
#define NACC   20                // 10 gram + 4 c1 + 4 c2 + n1 + n2
#define KCOMB  16
#define NBLK   (B * CH)          // 2048
#define TLEN4  ((T / CH) / 4)    // 250 float4 per chunk per stream (< 256: no loop)

// DPP controls
#define DPP_QX1   0xB1    // quad_perm(1,0,3,2)  == xor 1
#define DPP_QX2   0x4E    // quad_perm(2,3,0,1)  == xor 2
#define DPP_HMIRR 0x141   // row_half_mirror     (xor 4 within row of 16)
#define DPP_MIRR  0x140   // row_mirror          (xor 8 within row of 16)

template <int CTRL>
__device__ __forceinline__ float dpp_add(float v) {
    int x = __builtin_amdgcn_update_dpp(0, __float_as_int(v), CTRL, 0xF, 0xF, true);
    return v + __int_as_float(x);
}

__device__ __forceinline__ void accum20(float* __restrict__ acc,
        const float4 v0, const float4 v1, const float4 v2, const float4 v3,
        const float4 w1, const float4 w2)
{
    const float A0[4] = {v0.x, v0.y, v0.z, v0.w};
    const float A1[4] = {v1.x, v1.y, v1.z, v1.w};
    const float A2[4] = {v2.x, v2.y, v2.z, v2.w};
    const float A3[4] = {v3.x, v3.y, v3.z, v3.w};
    const float M1[4] = {w1.x, w1.y, w1.z, w1.w};
    const float M2[4] = {w2.x, w2.y, w2.z, w2.w};
#pragma unroll
    for (int j = 0; j < 4; j++) {
        float s0 = A0[j], s1 = A1[j], s2 = A2[j], s3 = A3[j];
        float x = M1[j], y = M2[j];
        acc[0]  = fmaf(s0, s0, acc[0]);
        acc[1]  = fmaf(s0, s1, acc[1]);
        acc[2]  = fmaf(s0, s2, acc[2]);
        acc[3]  = fmaf(s0, s3, acc[3]);
        acc[4]  = fmaf(s1, s1, acc[4]);
        acc[5]  = fmaf(s1, s2, acc[5]);
        acc[6]  = fmaf(s1, s3, acc[6]);
        acc[7]  = fmaf(s2, s2, acc[7]);
        acc[8]  = fmaf(s2, s3, acc[8]);
        acc[9]  = fmaf(s3, s3, acc[9]);
        acc[10] = fmaf(s0, x,  acc[10]);
        acc[11] = fmaf(s1, x,  acc[11]);
        acc[12] = fmaf(s2, x,  acc[12]);
        acc[13] = fmaf(s3, x,  acc[13]);
        acc[14] = fmaf(s0, y,  acc[14]);
        acc[15] = fmaf(s1, y,  acc[15]);
        acc[16] = fmaf(s2, y,  acc[16]);
        acc[17] = fmaf(s3, y,  acc[17]);
        acc[18] = fmaf(x,  x,  acc[18]);
        acc[19] = fmaf(y,  y,  acc[19]);
    }
}

// Partials layout: ws[a * NBLK + blk] (transposed) so finalize reads dense runs.
__global__ __launch_bounds__(256) void mixit_reduce_kernel(
    const float* __restrict__ est, const float* __restrict__ m1,
    const float* __restrict__ m2, float* __restrict__ ws)
{
    const int tid = threadIdx.x;
    const int b   = blockIdx.x / CH;
    const int ch  = blockIdx.x % CH;

    const float4* e0 = (const float4*)(est + (size_t)b * NSRC * T) + (size_t)ch * TLEN4;
    const float4* e1 = e0 + T / 4;
    const float4* e2 = e1 + T / 4;
    const float4* e3 = e2 + T / 4;
    const float4* p1 = (const float4*)(m1 + (size_t)b * T) + (size_t)ch * TLEN4;
    const float4* p2 = (const float4*)(m2 + (size_t)b * T) + (size_t)ch * TLEN4;

    float acc[NACC];
#pragma unroll
    for (int i = 0; i < NACC; i++) acc[i] = 0.0f;

    if (tid < TLEN4) {   // 250 of 256 threads load; single shot, no loop
        float4 v0 = e0[tid], v1 = e1[tid], v2 = e2[tid], v3 = e3[tid];
        float4 w1 = p1[tid], w2 = p2[tid];
        accum20(acc, v0, v1, v2, v3, w1, w2);
    }

    // wave reduce: 4 DPP adds (pure VALU) + one xor-16 swizzle ->
    // lanes 0 and 32 hold the two half-wave sums.
#pragma unroll
    for (int a = 0; a < NACC; a++) {
        float v = acc[a];
        v = dpp_add<DPP_QX1>(v);
        v = dpp_add<DPP_QX2>(v);
        v = dpp_add<DPP_HMIRR>(v);
        v = dpp_add<DPP_MIRR>(v);
        int x = __builtin_amdgcn_ds_swizzle(__float_as_int(v), 0x401F); // xor16
        acc[a] = v + __int_as_float(x);
    }

    const int lane = tid & 63;
    const int wave = tid >> 6;
    __shared__ float red[8][NACC];
    if (lane == 0 || lane == 32) {
        const int r = wave * 2 + (lane >> 5);
#pragma unroll
        for (int a = 0; a < NACC; a++) red[r][a] = acc[a];
    }
    __syncthreads();
    if (tid < NACC) {
        float s = 0.0f;
#pragma unroll
        for (int r = 0; r < 8; r++) s += red[r][tid];
        ws[(size_t)tid * NBLK + blockIdx.x] = s;   // deterministic, covers all slots
    }
}

__global__ __launch_bounds__(1024) void mixit_finalize_kernel(
    const float* __restrict__ ws, float* __restrict__ out)
{
    __shared__ float sums[B * NACC];     // [b*NACC + a]
    __shared__ float lkb[KCOMB * B];     // per (combo, batch) loss
    __shared__ float losses[KCOMB];

    const int t = threadIdx.x;

    // stage 1: 640 threads each sum one (a, b) run of CH=64 contiguous floats
    if (t < B * NACC) {
        const int a  = t >> 5;           // 0..19
        const int bb = t & 31;           // 0..31
        const float4* p = (const float4*)(ws + (size_t)a * NBLK + bb * CH);
        float4 s4 = p[0];
#pragma unroll
        for (int i = 1; i < CH / 4; i++) {
            float4 q = p[i];
            s4.x += q.x; s4.y += q.y; s4.z += q.z; s4.w += q.w;
        }
        sums[bb * NACC + a] = (s4.x + s4.y) + (s4.z + s4.w);
    }
    __syncthreads();

    // stage 2: 512 threads, one per (combo k, batch b)
    if (t < KCOMB * B) {
        const int k  = t >> 5;
        const int bb = t & 31;
        const float k0 = (float)((k >> 3) & 1);
        const float k1 = (float)((k >> 2) & 1);
        const float k2 = (float)((k >> 1) & 1);
        const float k3 = (float)(k & 1);
        const float u0 = 1.0f - k0, u1 = 1.0f - k1, u2 = 1.0f - k2, u3 = 1.0f - k3;

        const float* a = sums + bb * NACC;
        float g00 = a[0], g01 = a[1], g02 = a[2], g03 = a[3];
        float g11 = a[4], g12 = a[5], g13 = a[6];
        float g22 = a[7], g23 = a[8], g33 = a[9];

        float q0 = k0*k0*g00 + k1*k1*g11 + k2*k2*g22 + k3*k3*g33
                 + 2.0f*(k0*k1*g01 + k0*k2*g02 + k0*k3*g03
                       + k1*k2*g12 + k1*k3*g13 + k2*k3*g23);
        float q1 = u0*u0*g00 + u1*u1*g11 + u2*u2*g22 + u3*u3*g33
                 + 2.0f*(u0*u1*g01 + u0*u2*g02 + u0*u3*g03
                       + u1*u2*g12 + u1*u3*g13 + u2*u3*g23);
        float d1 = k0*a[10] + k1*a[11] + k2*a[12] + k3*a[13];
        float d2 = u0*a[14] + u1*a[15] + u2*a[16] + u3*a[17];

        float a0 = q0 - 2.0f*d1 + a[18];
        float a1 = q1 - 2.0f*d2 + a[19];

        // b==0 -> log10(0) = -inf -> loss = +inf (IEEE), never the min
        float l = 10.0f * (log10f(fmaf(30.0f, q0, a0)) - log10f(q0))
                + 10.0f * (log10f(fmaf(30.0f, q1, a1)) - log10f(q1));
        lkb[k * B + bb] = l;
    }
    __syncthreads();

    // stage 3: 16 threads sum over batches (serial, matches fp32 order closely)
    if (t < KCOMB) {
        float s = 0.0f;
#pragma unroll
        for (int bb = 0; bb < B; bb++) s += lkb[t * B + bb];
        losses[t] = s;
    }
    __syncthreads();

    // stage 4: first-occurrence argmin over 16 (matches jnp.argmin)
    if (t == 0) {
        float best = losses[0];
        int bi = 0;
        for (int k = 1; k < KCOMB; k++)
            if (losses[k] < best) { best = losses[k]; bi = k; }
        out[0] = (float)bi;
        out[1] = best;
    }
}

extern "C" void kernel_launch(void* const* d_in, const int* in_sizes, int n_in,
                              void* d_out, int out_size, void* d_ws, size_t ws_size,
                              hipStream_t stream) {
    const float* est = (const float*)d_in[0];
    const float* m1  = (const float*)d_in[1];
    const float* m2  = (const float*)d_in[2];
    float* ws  = (float*)d_ws;    // 20 * 2048 floats = 160 KB of partials
    float* out = (float*)d_out;

    mixit_reduce_kernel<<<NBLK, 256, 0, stream>>>(est, m1, m2, ws);
    mixit_finalize_kernel<<<1, 1024, 0, stream>>>(ws, out);
}